// Round 5
// baseline (121.553 us; speedup 1.0000x reference)
//
#include <hip/hip_runtime.h>

#define BATCH   8
#define SEQLEN  2048
#define DMODEL  1024
#define DSTATE  16
#define NC      64
#define TC      (SEQLEN / NC)          // 32
#define BLOCK   256
#define LOG2E   1.4426950408889634f

// ---------------------------------------------------------------------------
// Phase A: per-(b,d,chunk) local scan from h=0.
// u/delta: depth-8 register prefetch (3 rotating 4-step buffers, fully
// unrolled so all indices are compile-time). B tile staged in LDS once.
// Emits h_loc[16] + dsum per (b,d,chunk).
// ---------------------------------------------------------------------------
__global__ __launch_bounds__(BLOCK, 7) void ssm_phaseA(
    const float* __restrict__ u,  const float* __restrict__ de,
    const float* __restrict__ A,  const float* __restrict__ Bm,
    float* __restrict__ ws_h, float* __restrict__ ws_d)
{
    __shared__ float sB[TC * DSTATE];      // 2 KB
    const int tid = threadIdx.x;
    const int d   = blockIdx.x * BLOCK + tid;
    const int c   = blockIdx.y;
    const int b   = blockIdx.z;
    const int t0  = c * TC;

    if (tid < TC * DSTATE / 4)             // 128 float4s
        ((float4*)sB)[tid] =
            ((const float4*)(Bm + (size_t)(b * SEQLEN + t0) * DSTATE))[tid];

    float A2[DSTATE];
    #pragma unroll
    for (int n = 0; n < DSTATE; n += 4) {
        float4 a4 = *(const float4*)(A + (size_t)d * DSTATE + n);
        A2[n+0] = a4.x * LOG2E; A2[n+1] = a4.y * LOG2E;
        A2[n+2] = a4.z * LOG2E; A2[n+3] = a4.w * LOG2E;
    }
    float h[DSTATE];
    #pragma unroll
    for (int n = 0; n < DSTATE; ++n) h[n] = 0.f;
    float dsum = 0.f;

    const float* up = u  + (size_t)(b * SEQLEN + t0) * DMODEL + d;
    const float* dp = de + (size_t)(b * SEQLEN + t0) * DMODEL + d;

    __syncthreads();

    // 3 rotating buffers of 4 steps each: prefetch distance = 8 steps
    float ub[3][4], db[3][4];
    #pragma unroll
    for (int k = 0; k < 4; ++k) { ub[0][k] = up[(size_t)k * DMODEL];       db[0][k] = dp[(size_t)k * DMODEL]; }
    #pragma unroll
    for (int k = 0; k < 4; ++k) { ub[1][k] = up[(size_t)(4+k) * DMODEL];   db[1][k] = dp[(size_t)(4+k) * DMODEL]; }

    #pragma unroll
    for (int g = 0; g < TC / 4; ++g) {
        const int cur = g % 3;
        const int nxt = (g + 2) % 3;
        if (g + 2 < TC / 4) {
            #pragma unroll
            for (int k = 0; k < 4; ++k) {
                ub[nxt][k] = up[(size_t)((g+2)*4 + k) * DMODEL];
                db[nxt][k] = dp[(size_t)((g+2)*4 + k) * DMODEL];
            }
        }
        #pragma unroll
        for (int k = 0; k < 4; ++k) {
            const int t = g * 4 + k;
            const float dl = db[cur][k], uu = ub[cur][k];
            dsum += dl;
            const float du = dl * uu;
            #pragma unroll
            for (int n = 0; n < DSTATE; n += 4) {
                float4 b4 = *(const float4*)(sB + t * DSTATE + n);
                h[n+0] = __builtin_amdgcn_exp2f(dl * A2[n+0]) * h[n+0] + du * b4.x;
                h[n+1] = __builtin_amdgcn_exp2f(dl * A2[n+1]) * h[n+1] + du * b4.y;
                h[n+2] = __builtin_amdgcn_exp2f(dl * A2[n+2]) * h[n+2] + du * b4.z;
                h[n+3] = __builtin_amdgcn_exp2f(dl * A2[n+3]) * h[n+3] + du * b4.w;
            }
        }
    }

    float* wh = ws_h + (size_t)(b * NC + c) * DSTATE * DMODEL + d;
    #pragma unroll
    for (int n = 0; n < DSTATE; ++n) wh[(size_t)n * DMODEL] = h[n];
    ws_d[(size_t)(b * NC + c) * DMODEL + d] = dsum;
}

// ---------------------------------------------------------------------------
// Phase B: inter-chunk exclusive prefix scan, in place. One thread per
// (b,n,d) strand. ws data is L3-hot -> cheap.
// ---------------------------------------------------------------------------
__global__ __launch_bounds__(BLOCK) void ssm_phaseB(
    const float* __restrict__ A,
    float* __restrict__ ws_h, const float* __restrict__ ws_d)
{
    const int gid = blockIdx.x * BLOCK + threadIdx.x;   // (b, n, d)
    const int d  = gid % DMODEL;
    const int bn = gid / DMODEL;
    const int n  = bn % DSTATE;
    const int b  = bn / DSTATE;

    const float a2 = A[(size_t)d * DSTATE + n] * LOG2E;
    float h = 0.f;
    size_t ih = (size_t)b * NC * DSTATE * DMODEL + (size_t)n * DMODEL + d;
    size_t id = (size_t)b * NC * DMODEL + d;

    #pragma unroll 4
    for (int c = 0; c < NC; ++c) {
        float hl = ws_h[ih];
        float ds = ws_d[id];
        ws_h[ih] = h;                       // exclusive prefix
        h = __builtin_amdgcn_exp2f(a2 * ds) * h + hl;
        ih += (size_t)DSTATE * DMODEL;
        id += DMODEL;
    }
}

// ---------------------------------------------------------------------------
// Phase C: load incoming state, re-scan chunk, write y (non-temporal).
// Same deep-prefetch structure; B and C tiles staged in LDS.
// ---------------------------------------------------------------------------
__global__ __launch_bounds__(BLOCK, 6) void ssm_phaseC(
    const float* __restrict__ u,  const float* __restrict__ de,
    const float* __restrict__ A,  const float* __restrict__ Bm,
    const float* __restrict__ Cm, const float* __restrict__ Dv,
    const float* __restrict__ ws_h, float* __restrict__ y)
{
    __shared__ float sB[TC * DSTATE];      // 2 KB
    __shared__ float sC[TC * DSTATE];      // 2 KB
    const int tid = threadIdx.x;
    const int d   = blockIdx.x * BLOCK + tid;
    const int c   = blockIdx.y;
    const int b   = blockIdx.z;
    const int t0  = c * TC;

    if (tid < TC * DSTATE / 4)             // threads 0..127 -> B
        ((float4*)sB)[tid] =
            ((const float4*)(Bm + (size_t)(b * SEQLEN + t0) * DSTATE))[tid];
    else if (tid < 2 * (TC * DSTATE / 4))  // threads 128..255 -> C
        ((float4*)sC)[tid - TC*DSTATE/4] =
            ((const float4*)(Cm + (size_t)(b * SEQLEN + t0) * DSTATE))[tid - TC*DSTATE/4];

    float A2[DSTATE];
    #pragma unroll
    for (int n = 0; n < DSTATE; n += 4) {
        float4 a4 = *(const float4*)(A + (size_t)d * DSTATE + n);
        A2[n+0] = a4.x * LOG2E; A2[n+1] = a4.y * LOG2E;
        A2[n+2] = a4.z * LOG2E; A2[n+3] = a4.w * LOG2E;
    }

    float h[DSTATE];
    {
        const float* wh = ws_h + (size_t)(b * NC + c) * DSTATE * DMODEL + d;
        #pragma unroll
        for (int n = 0; n < DSTATE; ++n) h[n] = wh[(size_t)n * DMODEL];
    }

    const float Dd = Dv[d];
    const float* up = u  + (size_t)(b * SEQLEN + t0) * DMODEL + d;
    const float* dp = de + (size_t)(b * SEQLEN + t0) * DMODEL + d;
    float* yp = y + (size_t)(b * SEQLEN + t0) * DMODEL + d;

    __syncthreads();

    float ub[3][4], db[3][4];
    #pragma unroll
    for (int k = 0; k < 4; ++k) { ub[0][k] = up[(size_t)k * DMODEL];       db[0][k] = dp[(size_t)k * DMODEL]; }
    #pragma unroll
    for (int k = 0; k < 4; ++k) { ub[1][k] = up[(size_t)(4+k) * DMODEL];   db[1][k] = dp[(size_t)(4+k) * DMODEL]; }

    #pragma unroll
    for (int g = 0; g < TC / 4; ++g) {
        const int cur = g % 3;
        const int nxt = (g + 2) % 3;
        if (g + 2 < TC / 4) {
            #pragma unroll
            for (int k = 0; k < 4; ++k) {
                ub[nxt][k] = up[(size_t)((g+2)*4 + k) * DMODEL];
                db[nxt][k] = dp[(size_t)((g+2)*4 + k) * DMODEL];
            }
        }
        #pragma unroll
        for (int k = 0; k < 4; ++k) {
            const int t = g * 4 + k;
            const float dl = db[cur][k], uu = ub[cur][k];
            const float du = dl * uu;
            float acc = Dd * uu;
            #pragma unroll
            for (int n = 0; n < DSTATE; n += 4) {
                float4 b4 = *(const float4*)(sB + t * DSTATE + n);
                float4 c4 = *(const float4*)(sC + t * DSTATE + n);
                h[n+0] = __builtin_amdgcn_exp2f(dl * A2[n+0]) * h[n+0] + du * b4.x;
                h[n+1] = __builtin_amdgcn_exp2f(dl * A2[n+1]) * h[n+1] + du * b4.y;
                h[n+2] = __builtin_amdgcn_exp2f(dl * A2[n+2]) * h[n+2] + du * b4.z;
                h[n+3] = __builtin_amdgcn_exp2f(dl * A2[n+3]) * h[n+3] + du * b4.w;
                acc += h[n+0] * c4.x; acc += h[n+1] * c4.y;
                acc += h[n+2] * c4.z; acc += h[n+3] * c4.w;
            }
            __builtin_nontemporal_store(acc, yp + (size_t)t * DMODEL);
        }
    }
}

// ---------------------------------------------------------------------------
// Fallback: 1 thread per (b,d), full sequential scan. Correct but slow.
// ---------------------------------------------------------------------------
__global__ __launch_bounds__(BLOCK) void ssm_naive(
    const float* __restrict__ u,  const float* __restrict__ de,
    const float* __restrict__ A,  const float* __restrict__ Bm,
    const float* __restrict__ Cm, const float* __restrict__ Dv,
    float* __restrict__ y)
{
    const int tid = threadIdx.x;
    const int d   = blockIdx.x * BLOCK + tid;
    const int b   = blockIdx.z;

    float A2[DSTATE];
    #pragma unroll
    for (int n = 0; n < DSTATE; n += 4) {
        float4 a4 = *(const float4*)(A + (size_t)d * DSTATE + n);
        A2[n+0] = a4.x * LOG2E; A2[n+1] = a4.y * LOG2E;
        A2[n+2] = a4.z * LOG2E; A2[n+3] = a4.w * LOG2E;
    }
    float h[DSTATE];
    #pragma unroll
    for (int n = 0; n < DSTATE; ++n) h[n] = 0.f;
    const float Dd = Dv[d];

    const float* up = u  + (size_t)b * SEQLEN * DMODEL + d;
    const float* dp = de + (size_t)b * SEQLEN * DMODEL + d;
    float* yp = y + (size_t)b * SEQLEN * DMODEL + d;

    for (int t = 0; t < SEQLEN; ++t) {
        float dl = dp[(size_t)t * DMODEL];
        float uu = up[(size_t)t * DMODEL];
        float du  = dl * uu;
        float acc = Dd * uu;
        const float* bp = Bm + (size_t)(b * SEQLEN + t) * DSTATE;
        const float* cp = Cm + (size_t)(b * SEQLEN + t) * DSTATE;
        #pragma unroll
        for (int n = 0; n < DSTATE; n += 4) {
            float4 b4 = *(const float4*)(bp + n);
            float4 c4 = *(const float4*)(cp + n);
            h[n+0] = __builtin_amdgcn_exp2f(dl * A2[n+0]) * h[n+0] + du * b4.x;
            h[n+1] = __builtin_amdgcn_exp2f(dl * A2[n+1]) * h[n+1] + du * b4.y;
            h[n+2] = __builtin_amdgcn_exp2f(dl * A2[n+2]) * h[n+2] + du * b4.z;
            h[n+3] = __builtin_amdgcn_exp2f(dl * A2[n+3]) * h[n+3] + du * b4.w;
            acc += h[n+0] * c4.x;
            acc += h[n+1] * c4.y;
            acc += h[n+2] * c4.z;
            acc += h[n+3] * c4.w;
        }
        yp[(size_t)t * DMODEL] = acc;
    }
}

extern "C" void kernel_launch(void* const* d_in, const int* in_sizes, int n_in,
                              void* d_out, int out_size, void* d_ws, size_t ws_size,
                              hipStream_t stream) {
    const float* u  = (const float*)d_in[0];
    const float* de = (const float*)d_in[1];
    const float* A  = (const float*)d_in[2];
    const float* Bm = (const float*)d_in[3];
    const float* Cm = (const float*)d_in[4];
    const float* Dv = (const float*)d_in[5];
    float* y = (float*)d_out;

    const size_t n_wsh = (size_t)BATCH * NC * DSTATE * DMODEL;
    const size_t n_wsd = (size_t)BATCH * NC * DMODEL;
    const size_t need  = (n_wsh + n_wsd) * sizeof(float);

    if (ws_size >= need) {
        float* ws_h = (float*)d_ws;
        float* ws_d = ws_h + n_wsh;
        dim3 grid(DMODEL / BLOCK, NC, BATCH);
        ssm_phaseA<<<grid, BLOCK, 0, stream>>>(u, de, A, Bm, ws_h, ws_d);
        dim3 gridB((BATCH * DSTATE * DMODEL) / BLOCK, 1, 1);
        ssm_phaseB<<<gridB, BLOCK, 0, stream>>>(A, ws_h, ws_d);
        ssm_phaseC<<<grid, BLOCK, 0, stream>>>(u, de, A, Bm, Cm, Dv, ws_h, y);
    } else {
        dim3 grid(DMODEL / BLOCK, 1, BATCH);
        ssm_naive<<<grid, BLOCK, 0, stream>>>(u, de, A, Bm, Cm, Dv, y);
    }
}

// Round 6
// 117.954 us; speedup vs baseline: 1.0305x; 1.0305x over previous
//
#include <hip/hip_runtime.h>

#define BATCH   8
#define SEQLEN  2048
#define DMODEL  1024
#define DSTATE  16
#define BLOCK   256
#define LOG2E   1.4426950408889634f

// ---------------------------------------------------------------------------
// Phase A: per-(b,d,chunk) local scan from h=0. B tile staged in LDS
// (ds_reads get early fine-grained lgkmcnt scheduling), u/delta via depth-2
// clamped register prefetch. Emits h_loc[16] + dsum per (b,d,chunk).
// ---------------------------------------------------------------------------
template<int NC>
__global__ __launch_bounds__(BLOCK, 8) void ssm_phaseA(
    const float* __restrict__ u,  const float* __restrict__ de,
    const float* __restrict__ A,  const float* __restrict__ Bm,
    float* __restrict__ ws_h, float* __restrict__ ws_d)
{
    constexpr int TC = SEQLEN / NC;
    __shared__ float sB[TC * DSTATE];
    const int tid = threadIdx.x;
    const int d   = blockIdx.x * BLOCK + tid;
    const int c   = blockIdx.y;
    const int b   = blockIdx.z;
    const int t0  = c * TC;

    for (int i = tid; i < TC * DSTATE / 4; i += BLOCK)
        ((float4*)sB)[i] =
            ((const float4*)(Bm + (size_t)(b * SEQLEN + t0) * DSTATE))[i];

    float A2[DSTATE];
    #pragma unroll
    for (int n = 0; n < DSTATE; n += 4) {
        float4 a4 = *(const float4*)(A + (size_t)d * DSTATE + n);
        A2[n+0] = a4.x * LOG2E; A2[n+1] = a4.y * LOG2E;
        A2[n+2] = a4.z * LOG2E; A2[n+3] = a4.w * LOG2E;
    }
    float h[DSTATE];
    #pragma unroll
    for (int n = 0; n < DSTATE; ++n) h[n] = 0.f;
    float dsum = 0.f;

    const float* up = u  + (size_t)(b * SEQLEN + t0) * DMODEL + d;
    const float* dp = de + (size_t)(b * SEQLEN + t0) * DMODEL + d;

    __syncthreads();

    float u0 = up[0], d0 = dp[0];
    float u1 = up[DMODEL], d1 = dp[DMODEL];

    #pragma unroll
    for (int t = 0; t < TC; t += 2) {
        const int i2 = (t + 2 < TC) ? (t + 2) : (TC - 1);
        const int i3 = (t + 3 < TC) ? (t + 3) : (TC - 1);
        float u2 = up[(size_t)i2 * DMODEL], d2 = dp[(size_t)i2 * DMODEL];
        float u3 = up[(size_t)i3 * DMODEL], d3 = dp[(size_t)i3 * DMODEL];

        {
            dsum += d0;
            const float du = d0 * u0;
            #pragma unroll
            for (int n = 0; n < DSTATE; n += 4) {
                float4 b4 = *(const float4*)(sB + t * DSTATE + n);
                h[n+0] = __builtin_amdgcn_exp2f(d0 * A2[n+0]) * h[n+0] + du * b4.x;
                h[n+1] = __builtin_amdgcn_exp2f(d0 * A2[n+1]) * h[n+1] + du * b4.y;
                h[n+2] = __builtin_amdgcn_exp2f(d0 * A2[n+2]) * h[n+2] + du * b4.z;
                h[n+3] = __builtin_amdgcn_exp2f(d0 * A2[n+3]) * h[n+3] + du * b4.w;
            }
        }
        {
            dsum += d1;
            const float du = d1 * u1;
            #pragma unroll
            for (int n = 0; n < DSTATE; n += 4) {
                float4 b4 = *(const float4*)(sB + (t+1) * DSTATE + n);
                h[n+0] = __builtin_amdgcn_exp2f(d1 * A2[n+0]) * h[n+0] + du * b4.x;
                h[n+1] = __builtin_amdgcn_exp2f(d1 * A2[n+1]) * h[n+1] + du * b4.y;
                h[n+2] = __builtin_amdgcn_exp2f(d1 * A2[n+2]) * h[n+2] + du * b4.z;
                h[n+3] = __builtin_amdgcn_exp2f(d1 * A2[n+3]) * h[n+3] + du * b4.w;
            }
        }
        u0 = u2; d0 = d2; u1 = u3; d1 = d3;
    }

    float* wh = ws_h + (size_t)(b * NC + c) * DSTATE * DMODEL + d;
    #pragma unroll
    for (int n = 0; n < DSTATE; ++n) wh[(size_t)n * DMODEL] = h[n];
    ws_d[(size_t)(b * NC + c) * DMODEL + d] = dsum;
}

// ---------------------------------------------------------------------------
// Phase B: inter-chunk exclusive prefix scan, in place. One thread per
// (b,n,d) strand. ws data is L3-hot -> cheap.
// ---------------------------------------------------------------------------
template<int NC>
__global__ __launch_bounds__(BLOCK) void ssm_phaseB(
    const float* __restrict__ A,
    float* __restrict__ ws_h, const float* __restrict__ ws_d)
{
    const int gid = blockIdx.x * BLOCK + threadIdx.x;   // (b, n, d)
    const int d  = gid % DMODEL;
    const int bn = gid / DMODEL;
    const int n  = bn % DSTATE;
    const int b  = bn / DSTATE;

    const float a2 = A[(size_t)d * DSTATE + n] * LOG2E;
    float h = 0.f;
    size_t ih = (size_t)b * NC * DSTATE * DMODEL + (size_t)n * DMODEL + d;
    size_t id = (size_t)b * NC * DMODEL + d;

    #pragma unroll 4
    for (int c = 0; c < NC; ++c) {
        float hl = ws_h[ih];
        float ds = ws_d[id];
        ws_h[ih] = h;                       // exclusive prefix
        h = __builtin_amdgcn_exp2f(a2 * ds) * h + hl;
        ih += (size_t)DSTATE * DMODEL;
        id += DMODEL;
    }
}

// ---------------------------------------------------------------------------
// Phase C: load incoming state, re-scan chunk, write y (non-temporal).
// B and C tiles staged in LDS; depth-2 u/delta prefetch.
// ---------------------------------------------------------------------------
template<int NC>
__global__ __launch_bounds__(BLOCK, 7) void ssm_phaseC(
    const float* __restrict__ u,  const float* __restrict__ de,
    const float* __restrict__ A,  const float* __restrict__ Bm,
    const float* __restrict__ Cm, const float* __restrict__ Dv,
    const float* __restrict__ ws_h, float* __restrict__ y)
{
    constexpr int TC = SEQLEN / NC;
    __shared__ float sB[TC * DSTATE];
    __shared__ float sC[TC * DSTATE];
    const int tid = threadIdx.x;
    const int d   = blockIdx.x * BLOCK + tid;
    const int c   = blockIdx.y;
    const int b   = blockIdx.z;
    const int t0  = c * TC;

    for (int i = tid; i < TC * DSTATE / 4; i += BLOCK)
        ((float4*)sB)[i] =
            ((const float4*)(Bm + (size_t)(b * SEQLEN + t0) * DSTATE))[i];
    for (int i = tid; i < TC * DSTATE / 4; i += BLOCK)
        ((float4*)sC)[i] =
            ((const float4*)(Cm + (size_t)(b * SEQLEN + t0) * DSTATE))[i];

    float A2[DSTATE];
    #pragma unroll
    for (int n = 0; n < DSTATE; n += 4) {
        float4 a4 = *(const float4*)(A + (size_t)d * DSTATE + n);
        A2[n+0] = a4.x * LOG2E; A2[n+1] = a4.y * LOG2E;
        A2[n+2] = a4.z * LOG2E; A2[n+3] = a4.w * LOG2E;
    }

    float h[DSTATE];
    {
        const float* wh = ws_h + (size_t)(b * NC + c) * DSTATE * DMODEL + d;
        #pragma unroll
        for (int n = 0; n < DSTATE; ++n) h[n] = wh[(size_t)n * DMODEL];
    }

    const float Dd = Dv[d];
    const float* up = u  + (size_t)(b * SEQLEN + t0) * DMODEL + d;
    const float* dp = de + (size_t)(b * SEQLEN + t0) * DMODEL + d;
    float* yp = y + (size_t)(b * SEQLEN + t0) * DMODEL + d;

    __syncthreads();

    float u0 = up[0], d0 = dp[0];
    float u1 = up[DMODEL], d1 = dp[DMODEL];

    #pragma unroll
    for (int t = 0; t < TC; t += 2) {
        const int i2 = (t + 2 < TC) ? (t + 2) : (TC - 1);
        const int i3 = (t + 3 < TC) ? (t + 3) : (TC - 1);
        float u2 = up[(size_t)i2 * DMODEL], d2 = dp[(size_t)i2 * DMODEL];
        float u3 = up[(size_t)i3 * DMODEL], d3 = dp[(size_t)i3 * DMODEL];

        {
            const float du = d0 * u0;
            float acc = Dd * u0;
            #pragma unroll
            for (int n = 0; n < DSTATE; n += 4) {
                float4 b4 = *(const float4*)(sB + t * DSTATE + n);
                float4 c4 = *(const float4*)(sC + t * DSTATE + n);
                h[n+0] = __builtin_amdgcn_exp2f(d0 * A2[n+0]) * h[n+0] + du * b4.x;
                h[n+1] = __builtin_amdgcn_exp2f(d0 * A2[n+1]) * h[n+1] + du * b4.y;
                h[n+2] = __builtin_amdgcn_exp2f(d0 * A2[n+2]) * h[n+2] + du * b4.z;
                h[n+3] = __builtin_amdgcn_exp2f(d0 * A2[n+3]) * h[n+3] + du * b4.w;
                acc += h[n+0] * c4.x; acc += h[n+1] * c4.y;
                acc += h[n+2] * c4.z; acc += h[n+3] * c4.w;
            }
            __builtin_nontemporal_store(acc, yp + (size_t)t * DMODEL);
        }
        {
            const float du = d1 * u1;
            float acc = Dd * u1;
            #pragma unroll
            for (int n = 0; n < DSTATE; n += 4) {
                float4 b4 = *(const float4*)(sB + (t+1) * DSTATE + n);
                float4 c4 = *(const float4*)(sC + (t+1) * DSTATE + n);
                h[n+0] = __builtin_amdgcn_exp2f(d1 * A2[n+0]) * h[n+0] + du * b4.x;
                h[n+1] = __builtin_amdgcn_exp2f(d1 * A2[n+1]) * h[n+1] + du * b4.y;
                h[n+2] = __builtin_amdgcn_exp2f(d1 * A2[n+2]) * h[n+2] + du * b4.z;
                h[n+3] = __builtin_amdgcn_exp2f(d1 * A2[n+3]) * h[n+3] + du * b4.w;
                acc += h[n+0] * c4.x; acc += h[n+1] * c4.y;
                acc += h[n+2] * c4.z; acc += h[n+3] * c4.w;
            }
            __builtin_nontemporal_store(acc, yp + (size_t)(t+1) * DMODEL);
        }
        u0 = u2; d0 = d2; u1 = u3; d1 = d3;
    }
}

// ---------------------------------------------------------------------------
// Fallback: 1 thread per (b,d), full sequential scan. Correct but slow.
// ---------------------------------------------------------------------------
__global__ __launch_bounds__(BLOCK) void ssm_naive(
    const float* __restrict__ u,  const float* __restrict__ de,
    const float* __restrict__ A,  const float* __restrict__ Bm,
    const float* __restrict__ Cm, const float* __restrict__ Dv,
    float* __restrict__ y)
{
    const int tid = threadIdx.x;
    const int d   = blockIdx.x * BLOCK + tid;
    const int b   = blockIdx.z;

    float A2[DSTATE];
    #pragma unroll
    for (int n = 0; n < DSTATE; n += 4) {
        float4 a4 = *(const float4*)(A + (size_t)d * DSTATE + n);
        A2[n+0] = a4.x * LOG2E; A2[n+1] = a4.y * LOG2E;
        A2[n+2] = a4.z * LOG2E; A2[n+3] = a4.w * LOG2E;
    }
    float h[DSTATE];
    #pragma unroll
    for (int n = 0; n < DSTATE; ++n) h[n] = 0.f;
    const float Dd = Dv[d];

    const float* up = u  + (size_t)b * SEQLEN * DMODEL + d;
    const float* dp = de + (size_t)b * SEQLEN * DMODEL + d;
    float* yp = y + (size_t)b * SEQLEN * DMODEL + d;

    for (int t = 0; t < SEQLEN; ++t) {
        float dl = dp[(size_t)t * DMODEL];
        float uu = up[(size_t)t * DMODEL];
        float du  = dl * uu;
        float acc = Dd * uu;
        const float* bp = Bm + (size_t)(b * SEQLEN + t) * DSTATE;
        const float* cp = Cm + (size_t)(b * SEQLEN + t) * DSTATE;
        #pragma unroll
        for (int n = 0; n < DSTATE; n += 4) {
            float4 b4 = *(const float4*)(bp + n);
            float4 c4 = *(const float4*)(cp + n);
            h[n+0] = __builtin_amdgcn_exp2f(dl * A2[n+0]) * h[n+0] + du * b4.x;
            h[n+1] = __builtin_amdgcn_exp2f(dl * A2[n+1]) * h[n+1] + du * b4.y;
            h[n+2] = __builtin_amdgcn_exp2f(dl * A2[n+2]) * h[n+2] + du * b4.z;
            h[n+3] = __builtin_amdgcn_exp2f(dl * A2[n+3]) * h[n+3] + du * b4.w;
            acc += h[n+0] * c4.x;
            acc += h[n+1] * c4.y;
            acc += h[n+2] * c4.z;
            acc += h[n+3] * c4.w;
        }
        yp[(size_t)t * DMODEL] = acc;
    }
}

template<int NC>
static void launch_chunked(const float* u, const float* de, const float* A,
                           const float* Bm, const float* Cm, const float* Dv,
                           float* ws, float* y, hipStream_t stream) {
    float* ws_h = ws;
    float* ws_d = ws_h + (size_t)BATCH * NC * DSTATE * DMODEL;
    dim3 grid(DMODEL / BLOCK, NC, BATCH);
    ssm_phaseA<NC><<<grid, BLOCK, 0, stream>>>(u, de, A, Bm, ws_h, ws_d);
    dim3 gridB((BATCH * DSTATE * DMODEL) / BLOCK, 1, 1);
    ssm_phaseB<NC><<<gridB, BLOCK, 0, stream>>>(A, ws_h, ws_d);
    ssm_phaseC<NC><<<grid, BLOCK, 0, stream>>>(u, de, A, Bm, Cm, Dv, ws_h, y);
}

extern "C" void kernel_launch(void* const* d_in, const int* in_sizes, int n_in,
                              void* d_out, int out_size, void* d_ws, size_t ws_size,
                              hipStream_t stream) {
    const float* u  = (const float*)d_in[0];
    const float* de = (const float*)d_in[1];
    const float* A  = (const float*)d_in[2];
    const float* Bm = (const float*)d_in[3];
    const float* Cm = (const float*)d_in[4];
    const float* Dv = (const float*)d_in[5];
    float* y = (float*)d_out;

    auto need = [](int nc) {
        return ((size_t)BATCH * nc * DSTATE * DMODEL +
                (size_t)BATCH * nc * DMODEL) * sizeof(float);
    };

    if (ws_size >= need(128)) {
        launch_chunked<128>(u, de, A, Bm, Cm, Dv, (float*)d_ws, y, stream);
    } else if (ws_size >= need(64)) {
        launch_chunked<64>(u, de, A, Bm, Cm, Dv, (float*)d_ws, y, stream);
    } else {
        dim3 grid(DMODEL / BLOCK, 1, BATCH);
        ssm_naive<<<grid, BLOCK, 0, stream>>>(u, de, A, Bm, Cm, Dv, y);
    }
}